// Round 9
// baseline (31408.405 us; speedup 1.0000x reference)
//
#include <hip/hip_runtime.h>
#include <math.h>
#include <float.h>

#define VOCABSZ 50000
#define EMBSZ 128
#define HIDSZ 128
#define BSZ 16
#define TENCSZ 64
#define STEPSN 24
#define STARTTOK 2

#define ROWSB 64              // vocab rows per block
#define NBLK 782              // ceil(50000/64)
#define NSLOT (NBLK*4)        // per-wave partial slots (16 rows each)
#define RESCORE_DELTA 0.25f   // fp16-error margin for rescore candidates

// ws float layout
#define FEAT_OFF 0
#define HBUF_OFF (STEPSN*BSZ*256)                 // 98304
#define CBUF_OFF (HBUF_OFF + BSZ*HIDSZ)           // 100352
#define PMAX_OFF (CBUF_OFF + STEPSN*BSZ)          // 100736
#define PSUM_OFF (PMAX_OFF + NSLOT*BSZ)           // 150784
#define F16_OFF  (PSUM_OFF + NSLOT*BSZ)           // 200832 (halfs: 24*16*256)
#define W16_OFF  (F16_OFF + (STEPSN*BSZ*256)/2)   // 249984 (halfs: 50000*256)
#define WS_FLOATS (W16_OFF + (VOCABSZ*256)/2)

typedef _Float16 h2 __attribute__((ext_vector_type(2)));
union HU { uint4 u; h2 h[4]; _Float16 s[8]; };

static __device__ __forceinline__ float fdot2f(h2 a, h2 b, float c) {
#if __has_builtin(__builtin_amdgcn_fdot2)
  return __builtin_amdgcn_fdot2(a, b, c, false);
#else
  return c + (float)a.x * (float)b.x + (float)a.y * (float)b.y;
#endif
}

// bijective XCD swizzle: consecutive HW blocks round-robin XCDs; map so each
// XCD owns a CONTIGUOUS logical range (782 = 8*97 + 6, m204 recipe).
static __device__ __forceinline__ int xcd_logical(int bid) {
  const int q = NBLK / 8, r = NBLK % 8;          // 97, 6
  int xcd = bid & 7, loc = bid >> 3;
  return (xcd < r) ? xcd * (q + 1) + loc : r * (q + 1) + (xcd - r) * q + loc;
}

// ---------------------------------------------------------------------------
// conv: W_logit fp32 -> fp16 (one-time per call). 6250 blocks x 256.
// ---------------------------------------------------------------------------
__global__ __launch_bounds__(256) void conv_kernel(
    const float* __restrict__ Wl, _Float16* __restrict__ w16)
{
  int g = blockIdx.x * 256 + threadIdx.x;        // 1.6M threads, 8 elems each
  const float4* src = (const float4*)Wl;
  float4 x0 = src[(size_t)g * 2], x1 = src[(size_t)g * 2 + 1];
  HU o;
  o.s[0] = (_Float16)x0.x; o.s[1] = (_Float16)x0.y;
  o.s[2] = (_Float16)x0.z; o.s[3] = (_Float16)x0.w;
  o.s[4] = (_Float16)x1.x; o.s[5] = (_Float16)x1.y;
  o.s[6] = (_Float16)x1.z; o.s[7] = (_Float16)x1.w;
  ((uint4*)w16)[g] = o.u;
}

// ---------------------------------------------------------------------------
// Step kernel: fp16 dot2 GEMM. wave w: 16 rows; lane = r0*8+c; thread owns
// rows v1,v2 and k-chunks {j*8+c}. Writes fp32 logits to out[t], folds
// subtract of c[t-1], stores per-wave softmax partials (pmax/psum only).
// ---------------------------------------------------------------------------
__global__ __launch_bounds__(256, 3) void step_kernel(
    const float* __restrict__ bl,
    const float* __restrict__ ws_c, float* __restrict__ ws_f,
    float* __restrict__ out, int t)
{
  float* pmax = ws_f + PMAX_OFF;
  float* psum = ws_f + PSUM_OFF;
  const uint4* __restrict__ W16 = (const uint4*)(ws_c + W16_OFF);
  const uint4* __restrict__ F16 =
      (const uint4*)((const _Float16*)(ws_c + F16_OFF) + (size_t)t * BSZ * 256);

  const int tid = threadIdx.x;
  const int lane = tid & 63;
  const int w = tid >> 6;
  const int r0 = lane >> 3;
  const int c = lane & 7;
  const int logical = xcd_logical(blockIdx.x);
  const int v1 = logical * ROWSB + w * 16 + r0;
  const int v2 = v1 + 8;
  const bool val1 = v1 < VOCABSZ, val2 = v2 < VOCABSZ;
  const int v1c = val1 ? v1 : 0;
  const int v2c = val2 ? v2 : 0;

  // preload both W16 row slices: 8 uint4 in flight
  HU w1[4], w2[4];
#pragma unroll
  for (int j = 0; j < 4; ++j) w1[j].u = W16[(size_t)v1c * 32 + j * 8 + c];
#pragma unroll
  for (int j = 0; j < 4; ++j) w2[j].u = W16[(size_t)v2c * 32 + j * 8 + c];

  float acc1[BSZ], acc2[BSZ];
#pragma unroll
  for (int b = 0; b < BSZ; ++b) {
    HU f[4];
#pragma unroll
    for (int j = 0; j < 4; ++j) f[j].u = F16[b * 32 + j * 8 + c];
    float s1 = 0.f, s2 = 0.f;
#pragma unroll
    for (int j = 0; j < 4; ++j) {
#pragma unroll
      for (int p = 0; p < 4; ++p) {
        s1 = fdot2f(w1[j].h[p], f[j].h[p], s1);
        s2 = fdot2f(w2[j].h[p], f[j].h[p], s2);
      }
    }
    acc1[b] = s1; acc2[b] = s2;
  }

  // all-reduce over the 8 k-chunks (lane bits 0..2)
#pragma unroll
  for (int off = 1; off <= 4; off <<= 1) {
#pragma unroll
    for (int b = 0; b < BSZ; ++b) {
      acc1[b] += __shfl_xor(acc1[b], off);
      acc2[b] += __shfl_xor(acc2[b], off);
    }
  }
  const float lb1 = bl[v1c], lb2 = bl[v2c];
  const float* cb = ws_c + CBUF_OFF + (t - 1) * BSZ;
  const int slot = logical * 4 + w;

#pragma unroll
  for (int b = 0; b < BSZ; ++b) {
    float lg1 = acc1[b] + lb1;
    float lg2 = acc2[b] + lb2;
    if ((b & 7) == c) {
      if (val1) out[((size_t)t * BSZ + b) * VOCABSZ + v1] = lg1;
      if (val2) out[((size_t)t * BSZ + b) * VOCABSZ + v2] = lg2;
      if (t > 0) {
        float cv = cb[b];
        if (val1) { size_t i1 = ((size_t)(t - 1) * BSZ + b) * VOCABSZ + v1; out[i1] -= cv; }
        if (val2) { size_t i2 = ((size_t)(t - 1) * BSZ + b) * VOCABSZ + v2; out[i2] -= cv; }
      }
    }
    // wave partial (16 rows): max + sum-exp
    float m = val1 ? lg1 : -FLT_MAX;
    if (val2 && lg2 > m) m = lg2;
#pragma unroll
    for (int off = 8; off <= 32; off <<= 1) m = fmaxf(m, __shfl_xor(m, off));
    float s = (val1 ? __expf(lg1 - m) : 0.f) + (val2 ? __expf(lg2 - m) : 0.f);
#pragma unroll
    for (int off = 8; off <= 32; off <<= 1) s += __shfl_xor(s, off);
    if (lane == b) {
      pmax[b * NSLOT + slot] = m;
      psum[b * NSLOT + slot] = s;
    }
  }
}

// ---------------------------------------------------------------------------
// GRU + attention for one batch b; also emits fp16 feat for the step GEMM.
// ---------------------------------------------------------------------------
__device__ __forceinline__ void gru_attn(
    int tid, int b, int tok, int gstep,
    const float* __restrict__ enc, const float* __restrict__ inith,
    const float* __restrict__ embed,
    const float* __restrict__ W_ih, const float* __restrict__ W_hh,
    const float* __restrict__ b_ih, const float* __restrict__ b_hh,
    float* __restrict__ ws_f,
    float* s_emb, float* s_h, float* s_hnew, float* s_hg, float* s_probs)
{
  if (tid < 128) {
    s_emb[tid] = embed[(size_t)tok * EMBSZ + tid];
    s_h[tid] = (gstep == 0) ? inith[b * HIDSZ + tid]
                            : (ws_f + HBUF_OFF)[b * HIDSZ + tid];
  }
  __syncthreads();
  float xr = 0.f, xz = 0.f, xn = 0.f;
  if (tid < 128) {
    xr = b_ih[tid]; xz = b_ih[tid + 128]; xn = b_ih[tid + 256];
    const float4* wr = (const float4*)(W_ih + (size_t)tid * EMBSZ);
    const float4* wz = (const float4*)(W_ih + (size_t)(tid + 128) * EMBSZ);
    const float4* wn = (const float4*)(W_ih + (size_t)(tid + 256) * EMBSZ);
    const float4* e4 = (const float4*)s_emb;
#pragma unroll 8
    for (int k = 0; k < 32; ++k) {
      float4 e = e4[k], a = wr[k], bq = wz[k], cq = wn[k];
      xr += a.x * e.x + a.y * e.y + a.z * e.z + a.w * e.w;
      xz += bq.x * e.x + bq.y * e.y + bq.z * e.z + bq.w * e.w;
      xn += cq.x * e.x + cq.y * e.y + cq.z * e.z + cq.w * e.w;
    }
  } else {
    int j = tid - 128;
    float hr = b_hh[j], hz = b_hh[j + 128], hn = b_hh[j + 256];
    const float4* wr = (const float4*)(W_hh + (size_t)j * HIDSZ);
    const float4* wz = (const float4*)(W_hh + (size_t)(j + 128) * HIDSZ);
    const float4* wn = (const float4*)(W_hh + (size_t)(j + 256) * HIDSZ);
    const float4* h4 = (const float4*)s_h;
    float a1 = 0.f, a2 = 0.f, a3 = 0.f;
#pragma unroll 8
    for (int k = 0; k < 32; ++k) {
      float4 h = h4[k], a = wr[k], bq = wz[k], cq = wn[k];
      a1 += a.x * h.x + a.y * h.y + a.z * h.z + a.w * h.w;
      a2 += bq.x * h.x + bq.y * h.y + bq.z * h.z + bq.w * h.w;
      a3 += cq.x * h.x + cq.y * h.y + cq.z * h.z + cq.w * h.w;
    }
    s_hg[j] = hr + a1; s_hg[128 + j] = hz + a2; s_hg[256 + j] = hn + a3;
  }
  __syncthreads();
  if (tid < 128) {
    float r = 1.f / (1.f + expf(-(xr + s_hg[tid])));
    float z = 1.f / (1.f + expf(-(xz + s_hg[128 + tid])));
    float n = tanhf(xn + r * s_hg[256 + tid]);
    s_hnew[tid] = (1.f - z) * n + z * s_h[tid];
  }
  __syncthreads();
  if (tid < 64) {
    const float4* ep = (const float4*)(enc + ((size_t)b * TENCSZ + tid) * 256);
    const float4* h4 = (const float4*)s_hnew;
    float sc = 0.f;
#pragma unroll 8
    for (int k = 0; k < 32; ++k) {
      float4 e = ep[k], h = h4[k];
      sc += e.x * h.x + e.y * h.y + e.z * h.z + e.w * h.w;
    }
    float mx = sc;
#pragma unroll
    for (int off = 32; off; off >>= 1) mx = fmaxf(mx, __shfl_xor(mx, off));
    float p = expf(sc - mx);
    float su = p;
#pragma unroll
    for (int off = 32; off; off >>= 1) su += __shfl_xor(su, off);
    s_probs[tid] = p / su;
  }
  __syncthreads();
  if (tid < 128) {
    float a = 0.f;
#pragma unroll 8
    for (int tt = 0; tt < TENCSZ; ++tt)
      a += s_probs[tt] * enc[((size_t)b * TENCSZ + tt) * 256 + tid];
    float* fptr = ws_f + FEAT_OFF + ((size_t)gstep * BSZ + b) * 256;
    fptr[tid] = a;
    fptr[128 + tid] = s_hnew[tid];
    (ws_f + HBUF_OFF)[b * HIDSZ + tid] = s_hnew[tid];
    _Float16* f16 = (_Float16*)(ws_f + F16_OFF) + ((size_t)gstep * BSZ + b) * 256;
    f16[tid] = (_Float16)a;
    f16[128 + tid] = (_Float16)s_hnew[tid];
  }
}

// ---------------------------------------------------------------------------
// rg kernel: reduce partials -> c; fp32-RESCORE candidate slots -> exact
// token; then GRU+attention for gstep. grid = 16 blocks.
// ---------------------------------------------------------------------------
__global__ __launch_bounds__(256) void rg_kernel(
    const float* __restrict__ enc, const float* __restrict__ inith,
    const float* __restrict__ embed,
    const float* __restrict__ W_ih, const float* __restrict__ W_hh,
    const float* __restrict__ b_ih, const float* __restrict__ b_hh,
    const float* __restrict__ Wl, const float* __restrict__ bl,
    float* __restrict__ ws_f, float* __restrict__ out, int rstep, int gstep)
{
  const int b = blockIdx.x, tid = threadIdx.x;
  float* cbuf = ws_f + CBUF_OFF;
  float* pmax = ws_f + PMAX_OFF;
  float* psum = ws_f + PSUM_OFF;

  __shared__ float s_wm[4]; __shared__ int s_wi[4];
  __shared__ float s_ws[4];
  __shared__ int s_tok;
  __shared__ float s_emb[EMBSZ], s_h[HIDSZ], s_hnew[HIDSZ];
  __shared__ float s_hg[3 * HIDSZ], s_probs[TENCSZ];

  const int lane = tid & 63, wave = tid >> 6;

  if (rstep >= 0) {
    // global fp16-logit max
    float m = -FLT_MAX;
    for (int i = tid; i < NSLOT; i += 256) m = fmaxf(m, pmax[b * NSLOT + i]);
#pragma unroll
    for (int off = 32; off; off >>= 1) m = fmaxf(m, __shfl_xor(m, off));
    if (lane == 0) s_wm[wave] = m;
    __syncthreads();
    float gm = fmaxf(fmaxf(s_wm[0], s_wm[1]), fmaxf(s_wm[2], s_wm[3]));

    // sum-exp around gm
    float e = 0.f;
    for (int i = tid; i < NSLOT; i += 256)
      e += psum[b * NSLOT + i] * __expf(pmax[b * NSLOT + i] - gm);
#pragma unroll
    for (int off = 32; off; off >>= 1) e += __shfl_xor(e, off);
    if (lane == 0) s_ws[wave] = e;

    // fp32 rescore of candidate slots (fp16 slot-max >= gm - DELTA)
    const float* fr = ws_f + FEAT_OFF + ((size_t)rstep * BSZ + b) * 256;
    float best = -FLT_MAX; int bidx = 0x7fffffff;
    for (int i = tid; i < NSLOT; i += 256) {
      if (pmax[b * NSLOT + i] >= gm - RESCORE_DELTA) {
        int rowbase = (i >> 2) * ROWSB + (i & 3) * 16;
        for (int rr = 0; rr < 16; ++rr) {
          int v = rowbase + rr;
          if (v >= VOCABSZ) break;
          const float4* wr = (const float4*)(Wl + (size_t)v * 256);
          const float4* f4 = (const float4*)fr;
          float d = bl[v];
#pragma unroll 8
          for (int k = 0; k < 64; ++k) {
            float4 wv = wr[k], fv = f4[k];
            d += wv.x * fv.x + wv.y * fv.y + wv.z * fv.z + wv.w * fv.w;
          }
          if (d > best || (d == best && v < bidx)) { best = d; bidx = v; }
        }
      }
    }
#pragma unroll
    for (int off = 32; off; off >>= 1) {
      float ob = __shfl_xor(best, off); int oi = __shfl_xor(bidx, off);
      if (ob > best || (ob == best && oi < bidx)) { best = ob; bidx = oi; }
    }
    if (lane == 0) { s_wm[wave] = best; s_wi[wave] = bidx; }
    __syncthreads();
    if (tid == 0) {
      float gb = s_wm[0]; int gi = s_wi[0];
#pragma unroll
      for (int q = 1; q < 4; ++q)
        if (s_wm[q] > gb || (s_wm[q] == gb && s_wi[q] < gi)) { gb = s_wm[q]; gi = s_wi[q]; }
      float tot = s_ws[0] + s_ws[1] + s_ws[2] + s_ws[3];
      cbuf[rstep * BSZ + b] = gm + logf(tot);
      out[(size_t)STEPSN * BSZ * VOCABSZ + rstep * BSZ + b] = (float)gi;
      s_tok = gi;
    }
    __syncthreads();
  }

  if (gstep >= 0) {
    const int tok = (gstep == 0) ? STARTTOK : s_tok;
    gru_attn(tid, b, tok, gstep, enc, inith, embed, W_ih, W_hh, b_ih, b_hh,
             ws_f, s_emb, s_h, s_hnew, s_hg, s_probs);
  }
}

// ---------------------------------------------------------------------------
// Last-step subtract: out[23,b,v] -= c[23,b].
// ---------------------------------------------------------------------------
__global__ __launch_bounds__(256) void sub_last_kernel(
    const float* __restrict__ cbuf, float* __restrict__ out)
{
  size_t i = ((size_t)blockIdx.x * 256 + threadIdx.x) * 8;
  if (i >= (size_t)BSZ * VOCABSZ) return;
  int b = (int)(i / VOCABSZ);
  float cv = cbuf[(STEPSN - 1) * BSZ + b];
  float4* p = (float4*)(out + (size_t)(STEPSN - 1) * BSZ * VOCABSZ + i);
  float4 x0 = p[0], x1 = p[1];
  x0.x -= cv; x0.y -= cv; x0.z -= cv; x0.w -= cv;
  x1.x -= cv; x1.y -= cv; x1.z -= cv; x1.w -= cv;
  p[0] = x0; p[1] = x1;
}

extern "C" void kernel_launch(void* const* d_in, const int* in_sizes, int n_in,
                              void* d_out, int out_size, void* d_ws, size_t ws_size,
                              hipStream_t stream)
{
  const float* enc   = (const float*)d_in[0];
  const float* inith = (const float*)d_in[1];
  const float* embed = (const float*)d_in[2];
  const float* W_ih  = (const float*)d_in[3];
  const float* W_hh  = (const float*)d_in[4];
  const float* b_ih  = (const float*)d_in[5];
  const float* b_hh  = (const float*)d_in[6];
  const float* Wl    = (const float*)d_in[7];
  const float* bl    = (const float*)d_in[8];
  float* out = (float*)d_out;

  float* ws_f = (float*)d_ws;
  _Float16* w16 = (_Float16*)(ws_f + W16_OFF);

  conv_kernel<<<(VOCABSZ * 256 / 8) / 256, 256, 0, stream>>>(Wl, w16);
  rg_kernel<<<BSZ, 256, 0, stream>>>(enc, inith, embed, W_ih, W_hh, b_ih, b_hh,
                                     Wl, bl, ws_f, out, -1, 0);
  for (int t = 0; t < STEPSN; ++t) {
    step_kernel<<<NBLK, 256, 0, stream>>>(bl, ws_f, ws_f, out, t);
    rg_kernel<<<BSZ, 256, 0, stream>>>(enc, inith, embed, W_ih, W_hh, b_ih, b_hh,
                                       Wl, bl, ws_f, out, t,
                                       (t < STEPSN - 1) ? (t + 1) : -1);
  }
  const int nsub = (BSZ * VOCABSZ / 8 + 255) / 256;
  sub_last_kernel<<<nsub, 256, 0, stream>>>(ws_f + CBUF_OFF, out);
}

// Round 10
// 1665.102 us; speedup vs baseline: 18.8627x; 18.8627x over previous
//
#include <hip/hip_runtime.h>
#include <math.h>
#include <float.h>

#define VOCABSZ 50000
#define EMBSZ 128
#define HIDSZ 128
#define BSZ 16
#define TENCSZ 64
#define STEPSN 24
#define STARTTOK 2

#define ROWSB 64              // vocab rows per block
#define NBLK 782              // ceil(50000/64)
#define NSLOT (NBLK*4)        // per-wave partial slots (16 rows each)
#define RESCORE_DELTA 0.03f   // ~30x the fp16-quantization logit error bound
#define MAXCAND 256

// ws float layout
#define FEAT_OFF 0
#define HBUF_OFF (STEPSN*BSZ*256)                 // 98304
#define CBUF_OFF (HBUF_OFF + BSZ*HIDSZ)           // 100352
#define PMAX_OFF (CBUF_OFF + STEPSN*BSZ)          // 100736
#define PSUM_OFF (PMAX_OFF + NSLOT*BSZ)           // 150784
#define F16_OFF  (PSUM_OFF + NSLOT*BSZ)           // 200832 (halfs: 24*16*256)
#define W16_OFF  (F16_OFF + (STEPSN*BSZ*256)/2)   // 249984 (halfs: 50000*256)
#define WS_FLOATS (W16_OFF + (VOCABSZ*256)/2)

typedef _Float16 h2 __attribute__((ext_vector_type(2)));
union HU { uint4 u; h2 h[4]; _Float16 s[8]; };

static __device__ __forceinline__ float fdot2f(h2 a, h2 b, float c) {
#if __has_builtin(__builtin_amdgcn_fdot2)
  return __builtin_amdgcn_fdot2(a, b, c, false);
#else
  return c + (float)a.x * (float)b.x + (float)a.y * (float)b.y;
#endif
}

// bijective XCD swizzle (m204 recipe): each XCD owns a contiguous logical range.
static __device__ __forceinline__ int xcd_logical(int bid) {
  const int q = NBLK / 8, r = NBLK % 8;          // 97, 6
  int xcd = bid & 7, loc = bid >> 3;
  return (xcd < r) ? xcd * (q + 1) + loc : r * (q + 1) + (xcd - r) * q + loc;
}

// ---------------------------------------------------------------------------
// conv: W_logit fp32 -> fp16 (one-time per call). 6250 blocks x 256.
// ---------------------------------------------------------------------------
__global__ __launch_bounds__(256) void conv_kernel(
    const float* __restrict__ Wl, _Float16* __restrict__ w16)
{
  int g = blockIdx.x * 256 + threadIdx.x;
  const float4* src = (const float4*)Wl;
  float4 x0 = src[(size_t)g * 2], x1 = src[(size_t)g * 2 + 1];
  HU o;
  o.s[0] = (_Float16)x0.x; o.s[1] = (_Float16)x0.y;
  o.s[2] = (_Float16)x0.z; o.s[3] = (_Float16)x0.w;
  o.s[4] = (_Float16)x1.x; o.s[5] = (_Float16)x1.y;
  o.s[6] = (_Float16)x1.z; o.s[7] = (_Float16)x1.w;
  ((uint4*)w16)[g] = o.u;
}

// ---------------------------------------------------------------------------
// Step kernel: fp16 dot2 GEMM. wave w: 16 rows; lane = r0*8+c.
// Writes fp32 logits to out[t], folds subtract of c[t-1], stores per-wave
// softmax partials (pmax/psum).
// ---------------------------------------------------------------------------
__global__ __launch_bounds__(256, 3) void step_kernel(
    const float* __restrict__ bl,
    const float* __restrict__ ws_c, float* __restrict__ ws_f,
    float* __restrict__ out, int t)
{
  float* pmax = ws_f + PMAX_OFF;
  float* psum = ws_f + PSUM_OFF;
  const uint4* __restrict__ W16 = (const uint4*)(ws_c + W16_OFF);
  const uint4* __restrict__ F16 =
      (const uint4*)((const _Float16*)(ws_c + F16_OFF) + (size_t)t * BSZ * 256);

  const int tid = threadIdx.x;
  const int lane = tid & 63;
  const int w = tid >> 6;
  const int r0 = lane >> 3;
  const int c = lane & 7;
  const int logical = xcd_logical(blockIdx.x);
  const int v1 = logical * ROWSB + w * 16 + r0;
  const int v2 = v1 + 8;
  const bool val1 = v1 < VOCABSZ, val2 = v2 < VOCABSZ;
  const int v1c = val1 ? v1 : 0;
  const int v2c = val2 ? v2 : 0;

  HU w1[4], w2[4];
#pragma unroll
  for (int j = 0; j < 4; ++j) w1[j].u = W16[(size_t)v1c * 32 + j * 8 + c];
#pragma unroll
  for (int j = 0; j < 4; ++j) w2[j].u = W16[(size_t)v2c * 32 + j * 8 + c];

  float acc1[BSZ], acc2[BSZ];
#pragma unroll
  for (int b = 0; b < BSZ; ++b) {
    HU f[4];
#pragma unroll
    for (int j = 0; j < 4; ++j) f[j].u = F16[b * 32 + j * 8 + c];
    float s1 = 0.f, s2 = 0.f;
#pragma unroll
    for (int j = 0; j < 4; ++j) {
#pragma unroll
      for (int p = 0; p < 4; ++p) {
        s1 = fdot2f(w1[j].h[p], f[j].h[p], s1);
        s2 = fdot2f(w2[j].h[p], f[j].h[p], s2);
      }
    }
    acc1[b] = s1; acc2[b] = s2;
  }

#pragma unroll
  for (int off = 1; off <= 4; off <<= 1) {
#pragma unroll
    for (int b = 0; b < BSZ; ++b) {
      acc1[b] += __shfl_xor(acc1[b], off);
      acc2[b] += __shfl_xor(acc2[b], off);
    }
  }
  const float lb1 = bl[v1c], lb2 = bl[v2c];
  const float* cb = ws_c + CBUF_OFF + (t - 1) * BSZ;
  const int slot = logical * 4 + w;

#pragma unroll
  for (int b = 0; b < BSZ; ++b) {
    float lg1 = acc1[b] + lb1;
    float lg2 = acc2[b] + lb2;
    if ((b & 7) == c) {
      if (val1) out[((size_t)t * BSZ + b) * VOCABSZ + v1] = lg1;
      if (val2) out[((size_t)t * BSZ + b) * VOCABSZ + v2] = lg2;
      if (t > 0) {
        float cv = cb[b];
        if (val1) { size_t i1 = ((size_t)(t - 1) * BSZ + b) * VOCABSZ + v1; out[i1] -= cv; }
        if (val2) { size_t i2 = ((size_t)(t - 1) * BSZ + b) * VOCABSZ + v2; out[i2] -= cv; }
      }
    }
    float m = val1 ? lg1 : -FLT_MAX;
    if (val2 && lg2 > m) m = lg2;
#pragma unroll
    for (int off = 8; off <= 32; off <<= 1) m = fmaxf(m, __shfl_xor(m, off));
    float s = (val1 ? __expf(lg1 - m) : 0.f) + (val2 ? __expf(lg2 - m) : 0.f);
#pragma unroll
    for (int off = 8; off <= 32; off <<= 1) s += __shfl_xor(s, off);
    if (lane == b) {
      pmax[b * NSLOT + slot] = m;
      psum[b * NSLOT + slot] = s;
    }
  }
}

// ---------------------------------------------------------------------------
// GRU + attention for one batch b; also emits fp16 feat for the step GEMM.
// ---------------------------------------------------------------------------
__device__ __forceinline__ void gru_attn(
    int tid, int b, int tok, int gstep,
    const float* __restrict__ enc, const float* __restrict__ inith,
    const float* __restrict__ embed,
    const float* __restrict__ W_ih, const float* __restrict__ W_hh,
    const float* __restrict__ b_ih, const float* __restrict__ b_hh,
    float* __restrict__ ws_f,
    float* s_emb, float* s_h, float* s_hnew, float* s_hg, float* s_probs)
{
  if (tid < 128) {
    s_emb[tid] = embed[(size_t)tok * EMBSZ + tid];
    s_h[tid] = (gstep == 0) ? inith[b * HIDSZ + tid]
                            : (ws_f + HBUF_OFF)[b * HIDSZ + tid];
  }
  __syncthreads();
  float xr = 0.f, xz = 0.f, xn = 0.f;
  if (tid < 128) {
    xr = b_ih[tid]; xz = b_ih[tid + 128]; xn = b_ih[tid + 256];
    const float4* wr = (const float4*)(W_ih + (size_t)tid * EMBSZ);
    const float4* wz = (const float4*)(W_ih + (size_t)(tid + 128) * EMBSZ);
    const float4* wn = (const float4*)(W_ih + (size_t)(tid + 256) * EMBSZ);
    const float4* e4 = (const float4*)s_emb;
#pragma unroll 8
    for (int k = 0; k < 32; ++k) {
      float4 e = e4[k], a = wr[k], bq = wz[k], cq = wn[k];
      xr += a.x * e.x + a.y * e.y + a.z * e.z + a.w * e.w;
      xz += bq.x * e.x + bq.y * e.y + bq.z * e.z + bq.w * e.w;
      xn += cq.x * e.x + cq.y * e.y + cq.z * e.z + cq.w * e.w;
    }
  } else {
    int j = tid - 128;
    float hr = b_hh[j], hz = b_hh[j + 128], hn = b_hh[j + 256];
    const float4* wr = (const float4*)(W_hh + (size_t)j * HIDSZ);
    const float4* wz = (const float4*)(W_hh + (size_t)(j + 128) * HIDSZ);
    const float4* wn = (const float4*)(W_hh + (size_t)(j + 256) * HIDSZ);
    const float4* h4 = (const float4*)s_h;
    float a1 = 0.f, a2 = 0.f, a3 = 0.f;
#pragma unroll 8
    for (int k = 0; k < 32; ++k) {
      float4 h = h4[k], a = wr[k], bq = wz[k], cq = wn[k];
      a1 += a.x * h.x + a.y * h.y + a.z * h.z + a.w * h.w;
      a2 += bq.x * h.x + bq.y * h.y + bq.z * h.z + bq.w * h.w;
      a3 += cq.x * h.x + cq.y * h.y + cq.z * h.z + cq.w * h.w;
    }
    s_hg[j] = hr + a1; s_hg[128 + j] = hz + a2; s_hg[256 + j] = hn + a3;
  }
  __syncthreads();
  if (tid < 128) {
    float r = 1.f / (1.f + expf(-(xr + s_hg[tid])));
    float z = 1.f / (1.f + expf(-(xz + s_hg[128 + tid])));
    float n = tanhf(xn + r * s_hg[256 + tid]);
    s_hnew[tid] = (1.f - z) * n + z * s_h[tid];
  }
  __syncthreads();
  if (tid < 64) {
    const float4* ep = (const float4*)(enc + ((size_t)b * TENCSZ + tid) * 256);
    const float4* h4 = (const float4*)s_hnew;
    float sc = 0.f;
#pragma unroll 8
    for (int k = 0; k < 32; ++k) {
      float4 e = ep[k], h = h4[k];
      sc += e.x * h.x + e.y * h.y + e.z * h.z + e.w * h.w;
    }
    float mx = sc;
#pragma unroll
    for (int off = 32; off; off >>= 1) mx = fmaxf(mx, __shfl_xor(mx, off));
    float p = expf(sc - mx);
    float su = p;
#pragma unroll
    for (int off = 32; off; off >>= 1) su += __shfl_xor(su, off);
    s_probs[tid] = p / su;
  }
  __syncthreads();
  if (tid < 128) {
    float a = 0.f;
#pragma unroll 8
    for (int tt = 0; tt < TENCSZ; ++tt)
      a += s_probs[tt] * enc[((size_t)b * TENCSZ + tt) * 256 + tid];
    float* fptr = ws_f + FEAT_OFF + ((size_t)gstep * BSZ + b) * 256;
    fptr[tid] = a;
    fptr[128 + tid] = s_hnew[tid];
    (ws_f + HBUF_OFF)[b * HIDSZ + tid] = s_hnew[tid];
    _Float16* f16 = (_Float16*)(ws_f + F16_OFF) + ((size_t)gstep * BSZ + b) * 256;
    f16[tid] = (_Float16)a;
    f16[128 + tid] = (_Float16)s_hnew[tid];
  }
}

// ---------------------------------------------------------------------------
// rg kernel: reduce partials -> c; cooperative fp32 rescore of candidate
// slots -> exact token; then GRU+attention for gstep. grid = 16 blocks.
// ---------------------------------------------------------------------------
__global__ __launch_bounds__(256) void rg_kernel(
    const float* __restrict__ enc, const float* __restrict__ inith,
    const float* __restrict__ embed,
    const float* __restrict__ W_ih, const float* __restrict__ W_hh,
    const float* __restrict__ b_ih, const float* __restrict__ b_hh,
    const float* __restrict__ Wl, const float* __restrict__ bl,
    float* __restrict__ ws_f, float* __restrict__ out, int rstep, int gstep)
{
  const int b = blockIdx.x, tid = threadIdx.x;
  float* cbuf = ws_f + CBUF_OFF;
  float* pmax = ws_f + PMAX_OFF;
  float* psum = ws_f + PSUM_OFF;

  __shared__ float s_wm[4]; __shared__ int s_wi[4];
  __shared__ float s_ws[4];
  __shared__ int s_tok;
  __shared__ int s_cand[MAXCAND]; __shared__ int s_ncand;
  __shared__ float s_emb[EMBSZ], s_h[HIDSZ], s_hnew[HIDSZ];
  __shared__ float s_hg[3 * HIDSZ], s_probs[TENCSZ];

  const int lane = tid & 63, wave = tid >> 6;

  if (rstep >= 0) {
    if (tid == 0) s_ncand = 0;
    // global fp16-logit max
    float m = -FLT_MAX;
    for (int i = tid; i < NSLOT; i += 256) m = fmaxf(m, pmax[b * NSLOT + i]);
#pragma unroll
    for (int off = 32; off; off >>= 1) m = fmaxf(m, __shfl_xor(m, off));
    if (lane == 0) s_wm[wave] = m;
    __syncthreads();
    const float gm = fmaxf(fmaxf(s_wm[0], s_wm[1]), fmaxf(s_wm[2], s_wm[3]));

    // sum-exp around gm + candidate collection
    float e = 0.f;
    for (int i = tid; i < NSLOT; i += 256) {
      float pm = pmax[b * NSLOT + i];
      e += psum[b * NSLOT + i] * __expf(pm - gm);
      if (pm >= gm - RESCORE_DELTA) {
        int p = atomicAdd(&s_ncand, 1);
        if (p < MAXCAND) s_cand[p] = i;
      }
    }
#pragma unroll
    for (int off = 32; off; off >>= 1) e += __shfl_xor(e, off);
    if (lane == 0) s_ws[wave] = e;
    __syncthreads();

    // cooperative fp32 rescore: wave handles candidate ci = wave, wave+4, ...
    // lane = r*4 + kc: row rowbase+r, k-chunk kc (64 floats each).
    const float* fr = ws_f + FEAT_OFF + ((size_t)rstep * BSZ + b) * 256;
    const int nc_raw = s_ncand;
    const bool overflow = nc_raw > MAXCAND;
    const int nc = overflow ? NSLOT : nc_raw;
    const int r = lane >> 2, kc = lane & 3;
    float best = -FLT_MAX; int bidx = 0x7fffffff;
    for (int ci = wave; ci < nc; ci += 4) {
      const int slotid = overflow ? ci : s_cand[ci];
      const int v = (slotid >> 2) * ROWSB + (slotid & 3) * 16 + r;
      float d = 0.f;
      if (v < VOCABSZ) {
        const float4* wr = (const float4*)(Wl + (size_t)v * 256) + kc * 16;
        const float4* f4 = (const float4*)fr + kc * 16;
#pragma unroll
        for (int k = 0; k < 16; ++k) {
          float4 wv = wr[k], fv = f4[k];
          d += wv.x * fv.x + wv.y * fv.y + wv.z * fv.z + wv.w * fv.w;
        }
      }
      d += __shfl_xor(d, 1);
      d += __shfl_xor(d, 2);
      float mm; int mi;
      if (v < VOCABSZ) { mm = d + bl[v]; mi = v; }
      else { mm = -FLT_MAX; mi = 0x7fffffff; }
#pragma unroll
      for (int off = 4; off <= 32; off <<= 1) {
        float om = __shfl_xor(mm, off); int oi = __shfl_xor(mi, off);
        if (om > mm || (om == mm && oi < mi)) { mm = om; mi = oi; }
      }
      if (mm > best || (mm == best && mi < bidx)) { best = mm; bidx = mi; }
    }
    if (lane == 0) { s_wm[wave] = best; s_wi[wave] = bidx; }
    __syncthreads();
    if (tid == 0) {
      float gb = s_wm[0]; int gi = s_wi[0];
#pragma unroll
      for (int q = 1; q < 4; ++q)
        if (s_wm[q] > gb || (s_wm[q] == gb && s_wi[q] < gi)) { gb = s_wm[q]; gi = s_wi[q]; }
      float tot = s_ws[0] + s_ws[1] + s_ws[2] + s_ws[3];
      cbuf[rstep * BSZ + b] = gm + logf(tot);
      out[(size_t)STEPSN * BSZ * VOCABSZ + rstep * BSZ + b] = (float)gi;
      s_tok = gi;
    }
    __syncthreads();
  }

  if (gstep >= 0) {
    const int tok = (gstep == 0) ? STARTTOK : s_tok;
    gru_attn(tid, b, tok, gstep, enc, inith, embed, W_ih, W_hh, b_ih, b_hh,
             ws_f, s_emb, s_h, s_hnew, s_hg, s_probs);
  }
}

// ---------------------------------------------------------------------------
// Last-step subtract: out[23,b,v] -= c[23,b].
// ---------------------------------------------------------------------------
__global__ __launch_bounds__(256) void sub_last_kernel(
    const float* __restrict__ cbuf, float* __restrict__ out)
{
  size_t i = ((size_t)blockIdx.x * 256 + threadIdx.x) * 8;
  if (i >= (size_t)BSZ * VOCABSZ) return;
  int b = (int)(i / VOCABSZ);
  float cv = cbuf[(STEPSN - 1) * BSZ + b];
  float4* p = (float4*)(out + (size_t)(STEPSN - 1) * BSZ * VOCABSZ + i);
  float4 x0 = p[0], x1 = p[1];
  x0.x -= cv; x0.y -= cv; x0.z -= cv; x0.w -= cv;
  x1.x -= cv; x1.y -= cv; x1.z -= cv; x1.w -= cv;
  p[0] = x0; p[1] = x1;
}

extern "C" void kernel_launch(void* const* d_in, const int* in_sizes, int n_in,
                              void* d_out, int out_size, void* d_ws, size_t ws_size,
                              hipStream_t stream)
{
  const float* enc   = (const float*)d_in[0];
  const float* inith = (const float*)d_in[1];
  const float* embed = (const float*)d_in[2];
  const float* W_ih  = (const float*)d_in[3];
  const float* W_hh  = (const float*)d_in[4];
  const float* b_ih  = (const float*)d_in[5];
  const float* b_hh  = (const float*)d_in[6];
  const float* Wl    = (const float*)d_in[7];
  const float* bl    = (const float*)d_in[8];
  float* out = (float*)d_out;

  float* ws_f = (float*)d_ws;
  _Float16* w16 = (_Float16*)(ws_f + W16_OFF);

  conv_kernel<<<(VOCABSZ * 256 / 8) / 256, 256, 0, stream>>>(Wl, w16);
  rg_kernel<<<BSZ, 256, 0, stream>>>(enc, inith, embed, W_ih, W_hh, b_ih, b_hh,
                                     Wl, bl, ws_f, out, -1, 0);
  for (int t = 0; t < STEPSN; ++t) {
    step_kernel<<<NBLK, 256, 0, stream>>>(bl, ws_f, ws_f, out, t);
    rg_kernel<<<BSZ, 256, 0, stream>>>(enc, inith, embed, W_ih, W_hh, b_ih, b_hh,
                                       Wl, bl, ws_f, out, t,
                                       (t < STEPSN - 1) ? (t + 1) : -1);
  }
  const int nsub = (BSZ * VOCABSZ / 8 + 255) / 256;
  sub_last_kernel<<<nsub, 256, 0, stream>>>(ws_f + CBUF_OFF, out);
}

// Round 11
// 1474.297 us; speedup vs baseline: 21.3040x; 1.1294x over previous
//
#include <hip/hip_runtime.h>
#include <math.h>
#include <float.h>

#define VOCABSZ 50000
#define EMBSZ 128
#define HIDSZ 128
#define BSZ 16
#define TENCSZ 64
#define STEPSN 24
#define STARTTOK 2

#define ROWSB 64              // vocab rows per block
#define NBLK 782              // ceil(50000/64)
#define NSLOT (NBLK*4)        // per-wave partial slots (16 rows each)
#define RESCORE_DELTA 0.03f   // > 2x fp16-quantization logit error bound
#define MAXCAND 768
#define MAXROWS 256

// ws float layout
#define FEAT_OFF 0
#define HBUF_OFF (STEPSN*BSZ*256)                 // 98304
#define CBUF_OFF (HBUF_OFF + BSZ*HIDSZ)           // 100352
#define PMAX_OFF (CBUF_OFF + STEPSN*BSZ)          // 100736
#define PSUM_OFF (PMAX_OFF + NSLOT*BSZ)           // 150784
#define F16_OFF  (PSUM_OFF + NSLOT*BSZ)           // 200832 (halfs: 24*16*256)
#define W16_OFF  (F16_OFF + (STEPSN*BSZ*256)/2)   // 249984 (halfs: 50000*256)
#define WS_FLOATS (W16_OFF + (VOCABSZ*256)/2)

typedef _Float16 h2 __attribute__((ext_vector_type(2)));
union HU { uint4 u; h2 h[4]; _Float16 s[8]; };

static __device__ __forceinline__ float fdot2f(h2 a, h2 b, float c) {
#if __has_builtin(__builtin_amdgcn_fdot2)
  return __builtin_amdgcn_fdot2(a, b, c, false);
#else
  return c + (float)a.x * (float)b.x + (float)a.y * (float)b.y;
#endif
}

// bijective XCD swizzle (m204 recipe): each XCD owns a contiguous logical range.
static __device__ __forceinline__ int xcd_logical(int bid) {
  const int q = NBLK / 8, r = NBLK % 8;          // 97, 6
  int xcd = bid & 7, loc = bid >> 3;
  return (xcd < r) ? xcd * (q + 1) + loc : r * (q + 1) + (xcd - r) * q + loc;
}

// ---------------------------------------------------------------------------
// conv: W_logit fp32 -> fp16 (one-time per call). 6250 blocks x 256.
// ---------------------------------------------------------------------------
__global__ __launch_bounds__(256) void conv_kernel(
    const float* __restrict__ Wl, _Float16* __restrict__ w16)
{
  int g = blockIdx.x * 256 + threadIdx.x;
  const float4* src = (const float4*)Wl;
  float4 x0 = src[(size_t)g * 2], x1 = src[(size_t)g * 2 + 1];
  HU o;
  o.s[0] = (_Float16)x0.x; o.s[1] = (_Float16)x0.y;
  o.s[2] = (_Float16)x0.z; o.s[3] = (_Float16)x0.w;
  o.s[4] = (_Float16)x1.x; o.s[5] = (_Float16)x1.y;
  o.s[6] = (_Float16)x1.z; o.s[7] = (_Float16)x1.w;
  ((uint4*)w16)[g] = o.u;
}

// ---------------------------------------------------------------------------
// Step kernel: fp16 dot2 GEMM. wave w: 16 rows; lane = r0*8+c.
// Writes fp32 logits to out[t], folds subtract of c[t-1], stores per-wave
// softmax partials (pmax/psum).
// ---------------------------------------------------------------------------
__global__ __launch_bounds__(256, 3) void step_kernel(
    const float* __restrict__ bl,
    const float* __restrict__ ws_c, float* __restrict__ ws_f,
    float* __restrict__ out, int t)
{
  float* pmax = ws_f + PMAX_OFF;
  float* psum = ws_f + PSUM_OFF;
  const uint4* __restrict__ W16 = (const uint4*)(ws_c + W16_OFF);
  const uint4* __restrict__ F16 =
      (const uint4*)((const _Float16*)(ws_c + F16_OFF) + (size_t)t * BSZ * 256);

  const int tid = threadIdx.x;
  const int lane = tid & 63;
  const int w = tid >> 6;
  const int r0 = lane >> 3;
  const int c = lane & 7;
  const int logical = xcd_logical(blockIdx.x);
  const int v1 = logical * ROWSB + w * 16 + r0;
  const int v2 = v1 + 8;
  const bool val1 = v1 < VOCABSZ, val2 = v2 < VOCABSZ;
  const int v1c = val1 ? v1 : 0;
  const int v2c = val2 ? v2 : 0;

  HU w1[4], w2[4];
#pragma unroll
  for (int j = 0; j < 4; ++j) w1[j].u = W16[(size_t)v1c * 32 + j * 8 + c];
#pragma unroll
  for (int j = 0; j < 4; ++j) w2[j].u = W16[(size_t)v2c * 32 + j * 8 + c];

  float acc1[BSZ], acc2[BSZ];
#pragma unroll
  for (int b = 0; b < BSZ; ++b) {
    HU f[4];
#pragma unroll
    for (int j = 0; j < 4; ++j) f[j].u = F16[b * 32 + j * 8 + c];
    float s1 = 0.f, s2 = 0.f;
#pragma unroll
    for (int j = 0; j < 4; ++j) {
#pragma unroll
      for (int p = 0; p < 4; ++p) {
        s1 = fdot2f(w1[j].h[p], f[j].h[p], s1);
        s2 = fdot2f(w2[j].h[p], f[j].h[p], s2);
      }
    }
    acc1[b] = s1; acc2[b] = s2;
  }

#pragma unroll
  for (int off = 1; off <= 4; off <<= 1) {
#pragma unroll
    for (int b = 0; b < BSZ; ++b) {
      acc1[b] += __shfl_xor(acc1[b], off);
      acc2[b] += __shfl_xor(acc2[b], off);
    }
  }
  const float lb1 = bl[v1c], lb2 = bl[v2c];
  const float* cb = ws_c + CBUF_OFF + (t - 1) * BSZ;
  const int slot = logical * 4 + w;

#pragma unroll
  for (int b = 0; b < BSZ; ++b) {
    float lg1 = acc1[b] + lb1;
    float lg2 = acc2[b] + lb2;
    if ((b & 7) == c) {
      if (val1) out[((size_t)t * BSZ + b) * VOCABSZ + v1] = lg1;
      if (val2) out[((size_t)t * BSZ + b) * VOCABSZ + v2] = lg2;
      if (t > 0) {
        float cv = cb[b];
        if (val1) { size_t i1 = ((size_t)(t - 1) * BSZ + b) * VOCABSZ + v1; out[i1] -= cv; }
        if (val2) { size_t i2 = ((size_t)(t - 1) * BSZ + b) * VOCABSZ + v2; out[i2] -= cv; }
      }
    }
    float m = val1 ? lg1 : -FLT_MAX;
    if (val2 && lg2 > m) m = lg2;
#pragma unroll
    for (int off = 8; off <= 32; off <<= 1) m = fmaxf(m, __shfl_xor(m, off));
    float s = (val1 ? __expf(lg1 - m) : 0.f) + (val2 ? __expf(lg2 - m) : 0.f);
#pragma unroll
    for (int off = 8; off <= 32; off <<= 1) s += __shfl_xor(s, off);
    if (lane == b) {
      pmax[b * NSLOT + slot] = m;
      psum[b * NSLOT + slot] = s;
    }
  }
}

// ---------------------------------------------------------------------------
// GRU + attention for one batch b; also emits fp16 feat for the step GEMM.
// ---------------------------------------------------------------------------
__device__ __forceinline__ void gru_attn(
    int tid, int b, int tok, int gstep,
    const float* __restrict__ enc, const float* __restrict__ inith,
    const float* __restrict__ embed,
    const float* __restrict__ W_ih, const float* __restrict__ W_hh,
    const float* __restrict__ b_ih, const float* __restrict__ b_hh,
    float* __restrict__ ws_f,
    float* s_emb, float* s_h, float* s_hnew, float* s_hg, float* s_probs)
{
  if (tid < 128) {
    s_emb[tid] = embed[(size_t)tok * EMBSZ + tid];
    s_h[tid] = (gstep == 0) ? inith[b * HIDSZ + tid]
                            : (ws_f + HBUF_OFF)[b * HIDSZ + tid];
  }
  __syncthreads();
  float xr = 0.f, xz = 0.f, xn = 0.f;
  if (tid < 128) {
    xr = b_ih[tid]; xz = b_ih[tid + 128]; xn = b_ih[tid + 256];
    const float4* wr = (const float4*)(W_ih + (size_t)tid * EMBSZ);
    const float4* wz = (const float4*)(W_ih + (size_t)(tid + 128) * EMBSZ);
    const float4* wn = (const float4*)(W_ih + (size_t)(tid + 256) * EMBSZ);
    const float4* e4 = (const float4*)s_emb;
#pragma unroll 8
    for (int k = 0; k < 32; ++k) {
      float4 e = e4[k], a = wr[k], bq = wz[k], cq = wn[k];
      xr += a.x * e.x + a.y * e.y + a.z * e.z + a.w * e.w;
      xz += bq.x * e.x + bq.y * e.y + bq.z * e.z + bq.w * e.w;
      xn += cq.x * e.x + cq.y * e.y + cq.z * e.z + cq.w * e.w;
    }
  } else {
    int j = tid - 128;
    float hr = b_hh[j], hz = b_hh[j + 128], hn = b_hh[j + 256];
    const float4* wr = (const float4*)(W_hh + (size_t)j * HIDSZ);
    const float4* wz = (const float4*)(W_hh + (size_t)(j + 128) * HIDSZ);
    const float4* wn = (const float4*)(W_hh + (size_t)(j + 256) * HIDSZ);
    const float4* h4 = (const float4*)s_h;
    float a1 = 0.f, a2 = 0.f, a3 = 0.f;
#pragma unroll 8
    for (int k = 0; k < 32; ++k) {
      float4 h = h4[k], a = wr[k], bq = wz[k], cq = wn[k];
      a1 += a.x * h.x + a.y * h.y + a.z * h.z + a.w * h.w;
      a2 += bq.x * h.x + bq.y * h.y + bq.z * h.z + bq.w * h.w;
      a3 += cq.x * h.x + cq.y * h.y + cq.z * h.z + cq.w * h.w;
    }
    s_hg[j] = hr + a1; s_hg[128 + j] = hz + a2; s_hg[256 + j] = hn + a3;
  }
  __syncthreads();
  if (tid < 128) {
    float r = 1.f / (1.f + expf(-(xr + s_hg[tid])));
    float z = 1.f / (1.f + expf(-(xz + s_hg[128 + tid])));
    float n = tanhf(xn + r * s_hg[256 + tid]);
    s_hnew[tid] = (1.f - z) * n + z * s_h[tid];
  }
  __syncthreads();
  if (tid < 64) {
    const float4* ep = (const float4*)(enc + ((size_t)b * TENCSZ + tid) * 256);
    const float4* h4 = (const float4*)s_hnew;
    float sc = 0.f;
#pragma unroll 8
    for (int k = 0; k < 32; ++k) {
      float4 e = ep[k], h = h4[k];
      sc += e.x * h.x + e.y * h.y + e.z * h.z + e.w * h.w;
    }
    float mx = sc;
#pragma unroll
    for (int off = 32; off; off >>= 1) mx = fmaxf(mx, __shfl_xor(mx, off));
    float p = expf(sc - mx);
    float su = p;
#pragma unroll
    for (int off = 32; off; off >>= 1) su += __shfl_xor(su, off);
    s_probs[tid] = p / su;
  }
  __syncthreads();
  if (tid < 128) {
    float a = 0.f;
#pragma unroll 8
    for (int tt = 0; tt < TENCSZ; ++tt)
      a += s_probs[tt] * enc[((size_t)b * TENCSZ + tt) * 256 + tid];
    float* fptr = ws_f + FEAT_OFF + ((size_t)gstep * BSZ + b) * 256;
    fptr[tid] = a;
    fptr[128 + tid] = s_hnew[tid];
    (ws_f + HBUF_OFF)[b * HIDSZ + tid] = s_hnew[tid];
    _Float16* f16 = (_Float16*)(ws_f + F16_OFF) + ((size_t)gstep * BSZ + b) * 256;
    f16[tid] = (_Float16)a;
    f16[128 + tid] = (_Float16)s_hnew[tid];
  }
}

// ---------------------------------------------------------------------------
// rg kernel: reduce partials -> c; slot->row candidate narrowing via out[t];
// wave-cooperative per-row fp32 rescore -> exact token; then GRU+attention.
// grid = 16 blocks.
// ---------------------------------------------------------------------------
__global__ __launch_bounds__(256) void rg_kernel(
    const float* __restrict__ enc, const float* __restrict__ inith,
    const float* __restrict__ embed,
    const float* __restrict__ W_ih, const float* __restrict__ W_hh,
    const float* __restrict__ b_ih, const float* __restrict__ b_hh,
    const float* __restrict__ Wl, const float* __restrict__ bl,
    float* __restrict__ ws_f, float* __restrict__ out, int rstep, int gstep)
{
  const int b = blockIdx.x, tid = threadIdx.x;
  float* cbuf = ws_f + CBUF_OFF;
  float* pmax = ws_f + PMAX_OFF;
  float* psum = ws_f + PSUM_OFF;

  __shared__ float s_wm[4]; __shared__ int s_wi[4];
  __shared__ float s_ws[4];
  __shared__ int s_tok;
  __shared__ int s_cand[MAXCAND]; __shared__ int s_ncand;
  __shared__ int s_rows[MAXROWS]; __shared__ int s_nrows;
  __shared__ float s_emb[EMBSZ], s_h[HIDSZ], s_hnew[HIDSZ];
  __shared__ float s_hg[3 * HIDSZ], s_probs[TENCSZ];

  const int lane = tid & 63, wave = tid >> 6;

  if (rstep >= 0) {
    if (tid == 0) { s_ncand = 0; s_nrows = 0; }
    // global fp16-logit max
    float m = -FLT_MAX;
    for (int i = tid; i < NSLOT; i += 256) m = fmaxf(m, pmax[b * NSLOT + i]);
#pragma unroll
    for (int off = 32; off; off >>= 1) m = fmaxf(m, __shfl_xor(m, off));
    if (lane == 0) s_wm[wave] = m;
    __syncthreads();
    const float gm = fmaxf(fmaxf(s_wm[0], s_wm[1]), fmaxf(s_wm[2], s_wm[3]));
    const float thresh = gm - RESCORE_DELTA;

    // sum-exp around gm + candidate slot collection
    float e = 0.f;
    for (int i = tid; i < NSLOT; i += 256) {
      float pm = pmax[b * NSLOT + i];
      e += psum[b * NSLOT + i] * __expf(pm - gm);
      if (pm >= thresh) {
        int p = atomicAdd(&s_ncand, 1);
        if (p < MAXCAND) s_cand[p] = i;
      }
    }
#pragma unroll
    for (int off = 32; off; off >>= 1) e += __shfl_xor(e, off);
    if (lane == 0) s_ws[wave] = e;
    __syncthreads();

    const float* lrow = out + ((size_t)rstep * BSZ + b) * VOCABSZ;
    const int nc_raw = s_ncand;
    const bool ovf = nc_raw > MAXCAND;
    const int nc = ovf ? NSLOT : nc_raw;

    // ---- phase 3: thread-parallel slot->row narrowing (reads out[t]) ----
    for (int ci = tid; ci < nc; ci += 256) {
      const int slotid = ovf ? ci : s_cand[ci];
      if (ovf && pmax[b * NSLOT + slotid] < thresh) continue;
      const int rowbase = (slotid >> 2) * ROWSB + (slotid & 3) * 16;
      if (rowbase >= VOCABSZ) continue;
      const float4* orow = (const float4*)(lrow + rowbase);
      float4 q[4];
#pragma unroll
      for (int j = 0; j < 4; ++j) q[j] = orow[j];
#pragma unroll
      for (int j = 0; j < 4; ++j) {
        const float vv[4] = {q[j].x, q[j].y, q[j].z, q[j].w};
#pragma unroll
        for (int k = 0; k < 4; ++k) {
          if (vv[k] >= thresh) {
            int p = atomicAdd(&s_nrows, 1);
            if (p < MAXROWS) s_rows[p] = rowbase + j * 4 + k;
          }
        }
      }
    }
    __syncthreads();

    const float* fr = ws_f + FEAT_OFF + ((size_t)rstep * BSZ + b) * 256;
    float best = -FLT_MAX; int bidx = 0x7fffffff;

    if (s_nrows <= MAXROWS) {
      // ---- phase 4: wave-cooperative per-row fp32 rescore ----
      const float4 fv = ((const float4*)fr)[lane];
      const int nrows = s_nrows;
      for (int ri = wave; ri < nrows; ri += 4) {
        const int v = s_rows[ri];
        const float4 wv = ((const float4*)(Wl + (size_t)v * 256))[lane];
        float d = wv.x * fv.x + wv.y * fv.y + wv.z * fv.z + wv.w * fv.w;
#pragma unroll
        for (int off = 1; off <= 32; off <<= 1) d += __shfl_xor(d, off);
        d += bl[v];
        if (d > best || (d == best && v < bidx)) { best = d; bidx = v; }
      }
    } else {
      // ---- fallback: wave-per-slot rescore (complete coverage) ----
      const int r = lane >> 2, kc = lane & 3;
      for (int ci = wave; ci < nc; ci += 4) {
        const int slotid = ovf ? ci : s_cand[ci];
        if (ovf && pmax[b * NSLOT + slotid] < thresh) continue;
        const int v = (slotid >> 2) * ROWSB + (slotid & 3) * 16 + r;
        float d = 0.f;
        if (v < VOCABSZ) {
          const float4* wr = (const float4*)(Wl + (size_t)v * 256) + kc * 16;
          const float4* f4 = (const float4*)fr + kc * 16;
#pragma unroll
          for (int k = 0; k < 16; ++k) {
            float4 wv = wr[k], fvv = f4[k];
            d += wv.x * fvv.x + wv.y * fvv.y + wv.z * fvv.z + wv.w * fvv.w;
          }
        }
        d += __shfl_xor(d, 1);
        d += __shfl_xor(d, 2);
        float mm; int mi;
        if (v < VOCABSZ) { mm = d + bl[v]; mi = v; }
        else { mm = -FLT_MAX; mi = 0x7fffffff; }
#pragma unroll
        for (int off = 4; off <= 32; off <<= 1) {
          float om = __shfl_xor(mm, off); int oi = __shfl_xor(mi, off);
          if (om > mm || (om == mm && oi < mi)) { mm = om; mi = oi; }
        }
        if (mm > best || (mm == best && mi < bidx)) { best = mm; bidx = mi; }
      }
    }
    if (lane == 0) { s_wm[wave] = best; s_wi[wave] = bidx; }
    __syncthreads();
    if (tid == 0) {
      float gb = s_wm[0]; int gi = s_wi[0];
#pragma unroll
      for (int q = 1; q < 4; ++q)
        if (s_wm[q] > gb || (s_wm[q] == gb && s_wi[q] < gi)) { gb = s_wm[q]; gi = s_wi[q]; }
      float tot = s_ws[0] + s_ws[1] + s_ws[2] + s_ws[3];
      cbuf[rstep * BSZ + b] = gm + logf(tot);
      out[(size_t)STEPSN * BSZ * VOCABSZ + rstep * BSZ + b] = (float)gi;
      s_tok = gi;
    }
    __syncthreads();
  }

  if (gstep >= 0) {
    const int tok = (gstep == 0) ? STARTTOK : s_tok;
    gru_attn(tid, b, tok, gstep, enc, inith, embed, W_ih, W_hh, b_ih, b_hh,
             ws_f, s_emb, s_h, s_hnew, s_hg, s_probs);
  }
}

// ---------------------------------------------------------------------------
// Last-step subtract: out[23,b,v] -= c[23,b].
// ---------------------------------------------------------------------------
__global__ __launch_bounds__(256) void sub_last_kernel(
    const float* __restrict__ cbuf, float* __restrict__ out)
{
  size_t i = ((size_t)blockIdx.x * 256 + threadIdx.x) * 8;
  if (i >= (size_t)BSZ * VOCABSZ) return;
  int b = (int)(i / VOCABSZ);
  float cv = cbuf[(STEPSN - 1) * BSZ + b];
  float4* p = (float4*)(out + (size_t)(STEPSN - 1) * BSZ * VOCABSZ + i);
  float4 x0 = p[0], x1 = p[1];
  x0.x -= cv; x0.y -= cv; x0.z -= cv; x0.w -= cv;
  x1.x -= cv; x1.y -= cv; x1.z -= cv; x1.w -= cv;
  p[0] = x0; p[1] = x1;
}

extern "C" void kernel_launch(void* const* d_in, const int* in_sizes, int n_in,
                              void* d_out, int out_size, void* d_ws, size_t ws_size,
                              hipStream_t stream)
{
  const float* enc   = (const float*)d_in[0];
  const float* inith = (const float*)d_in[1];
  const float* embed = (const float*)d_in[2];
  const float* W_ih  = (const float*)d_in[3];
  const float* W_hh  = (const float*)d_in[4];
  const float* b_ih  = (const float*)d_in[5];
  const float* b_hh  = (const float*)d_in[6];
  const float* Wl    = (const float*)d_in[7];
  const float* bl    = (const float*)d_in[8];
  float* out = (float*)d_out;

  float* ws_f = (float*)d_ws;
  _Float16* w16 = (_Float16*)(ws_f + W16_OFF);

  conv_kernel<<<(VOCABSZ * 256 / 8) / 256, 256, 0, stream>>>(Wl, w16);
  rg_kernel<<<BSZ, 256, 0, stream>>>(enc, inith, embed, W_ih, W_hh, b_ih, b_hh,
                                     Wl, bl, ws_f, out, -1, 0);
  for (int t = 0; t < STEPSN; ++t) {
    step_kernel<<<NBLK, 256, 0, stream>>>(bl, ws_f, ws_f, out, t);
    rg_kernel<<<BSZ, 256, 0, stream>>>(enc, inith, embed, W_ih, W_hh, b_ih, b_hh,
                                       Wl, bl, ws_f, out, t,
                                       (t < STEPSN - 1) ? (t + 1) : -1);
  }
  const int nsub = (BSZ * VOCABSZ / 8 + 255) / 256;
  sub_last_kernel<<<nsub, 256, 0, stream>>>(ws_f + CBUF_OFF, out);
}